// Round 14
// baseline (414.661 us; speedup 1.0000x reference)
//
#include <hip/hip_runtime.h>
#include <hip/hip_bf16.h>
#include <stdint.h>

// ---------------- problem dims ----------------
#define BTOT   65536
#define DIN    784
#define NH1    256
#define NH2    64
#define NEXP   10
#define BM     256
#define NKS1   25      // K1 = 800 (784 + bias row @784 + zeros), 25 steps of 32

// ---------------- LDS layout (bytes) ----------------
// W-only 3-slot ring, 16 KB/slot. h (64 KB) overlays the ring (epilogue only).
#define SLOT(s)   (lds + (s) * 16384)
#define EXPL_OFF  65536                    // [256 m][10 e] f32 = 10240
#define B2S_OFF   75776                    // [10][64] f32 = 2560
#define W3S_OFF   78336                    // [10][64] f32 = 2560
#define B3S_OFF   80896                    // 64
#define BG2S_OFF  80960                    // 64
#define LDS_TOTAL 81024

typedef short s16x8  __attribute__((ext_vector_type(8)));
typedef float f32x4  __attribute__((ext_vector_type(4)));
typedef float f32x16 __attribute__((ext_vector_type(16)));

__device__ __forceinline__ short bf16b(float v) {
    __bf16 b = (__bf16)v;
    return __builtin_bit_cast(short, b);
}

__device__ __forceinline__ void g2l16(const void* g, void* l) {
    __builtin_amdgcn_global_load_lds(
        (const __attribute__((address_space(1))) unsigned char*)g,
        (__attribute__((address_space(3))) unsigned char*)l, 16, 0, 0);
}

// ---------------- prep: fragment-order weights (bf16, b1 folded) ------------
// w1t [e11][ks25][nb8][kh2][lane64][8]: n=nb*32+(lane&31),
// k=ks*32+kh*16+(lane>>5)*8+j; k==784 -> bias; e==10 -> gate Wg1/bg1.
__global__ void prep_w1(const float* __restrict__ W1, const float* __restrict__ b1,
                        const float* __restrict__ Wg1, const float* __restrict__ bg1,
                        __bf16* __restrict__ dst) {
    int t = blockIdx.x * 256 + threadIdx.x;          // < 281600
    int lane = t & 63;
    int kh = (t >> 6) & 1;
    int nb = (t >> 7) & 7;
    int r  = t >> 10;
    int ks = r % 25, e = r / 25;
    int n  = nb * 32 + (lane & 31);
    int k0 = ks * 32 + kh * 16 + (lane >> 5) * 8;
    const float* src  = (e < NEXP) ? (W1 + (size_t)e * DIN * NH1) : Wg1;
    const float* bias = (e < NEXP) ? (b1 + e * NH1) : bg1;
    s16x8 o;
    #pragma unroll
    for (int j = 0; j < 8; ++j) {
        int k = k0 + j;
        float v = (k < DIN) ? src[(size_t)k * NH1 + n]
                            : ((k == DIN) ? bias[n] : 0.f);
        o[j] = bf16b(v);
    }
    *(s16x8*)((short*)dst + (size_t)t * 8) = o;
}

// w2t [e10][jb2][ks8][kh2][lane64][8]: n=jb*32+(lane&31), K2=256.
__global__ void prep_w2(const float* __restrict__ W2, __bf16* __restrict__ dst) {
    int t = blockIdx.x * 256 + threadIdx.x;          // < 20480
    int lane = t & 63;
    int kh = (t >> 6) & 1;
    int ks = (t >> 7) & 7;
    int jb = (t >> 10) & 1;
    int e  = t >> 11;
    int n  = jb * 32 + (lane & 31);
    int k0 = ks * 32 + kh * 16 + (lane >> 5) * 8;
    s16x8 o;
    #pragma unroll
    for (int j = 0; j < 8; ++j)
        o[j] = bf16b(W2[((size_t)e * NH1 + k0 + j) * NH2 + n]);
    *(s16x8*)((short*)dst + (size_t)t * 8) = o;
}

// wg2t [ks8][kh2][lane64][8]: col = lane&31 (valid <10), K2=256.
__global__ void prep_wg2(const float* __restrict__ Wg2, __bf16* __restrict__ dst) {
    int t = blockIdx.x * 256 + threadIdx.x;
    if (t >= 1024) return;
    int lane = t & 63;
    int kh = (t >> 6) & 1;
    int ks = t >> 7;
    int n  = lane & 31;
    int k0 = ks * 32 + kh * 16 + (lane >> 5) * 8;
    s16x8 o;
    #pragma unroll
    for (int j = 0; j < 8; ++j)
        o[j] = bf16b((n < NEXP) ? Wg2[(size_t)(k0 + j) * NEXP + n] : 0.f);
    *(s16x8*)((short*)dst + (size_t)t * 8) = o;
}

// prep_x: x fp32 -> bf16 fragment-order [rb256][ks25][mq8][kh2][hw2][row32][j8]
__global__ void prep_x(const float* __restrict__ x, __bf16* __restrict__ dst) {
    __shared__ short xl[32 * 800];
    const int rb = blockIdx.x >> 3, mq = blockIdx.x & 7;
    const int tid = threadIdx.x;
    const float* xg = x + ((size_t)rb * 256 + mq * 32) * DIN;
    #pragma unroll 4
    for (int i = 0; i < 25; ++i) {                   // 32*196 = 6272 float4
        int idx = tid + i * 256;
        if (idx < 6272) {
            int r = idx / 196, c = (idx % 196) * 4;
            float4 v = *(const float4*)(xg + (size_t)r * DIN + c);
            uint2 w; short* p = (short*)&w;
            p[0] = bf16b(v.x); p[1] = bf16b(v.y);
            p[2] = bf16b(v.z); p[3] = bf16b(v.w);
            *(uint2*)(xl + r * 800 + c) = w;
        }
    }
    for (int i = tid; i < 32 * 16; i += 256) {       // k=784 bias-1, 785..799 zeros
        int r = i >> 4, k = DIN + (i & 15);
        xl[r * 800 + k] = (k == DIN) ? bf16b(1.f) : (short)0;
    }
    __syncthreads();
    #pragma unroll 2
    for (int i = 0; i < 13; ++i) {                   // 3200 x 16B chunks
        int idx = tid + i * 256;
        if (idx < 3200) {
            int row = idx & 31, c8 = idx >> 5;       // c8 in [0,100)
            int ks = c8 >> 2, rem = c8 & 3;
            int kh = rem >> 1, hw = rem & 1;
            s16x8 v = *(const s16x8*)(xl + row * 800 + ks * 32 + kh * 16 + hw * 8);
            *(s16x8*)((char*)dst + (((size_t)(rb * 25 + ks) * 8 + mq) * 2048)
                      + kh * 1024 + hw * 512 + row * 16) = v;
        }
    }
}

// ---- staging + body macros ----
// x prefetch: 4 global b128 loads straight into xr[P] (compiler-tracked vmcnt).
#define XPF(P, KS) {                                                          \
        const char* xp_ = xtc + ((size_t)(KS) << 14) + mw * 4096 + lane * 16; \
        xr[P][0][0] = *(const s16x8*)(xp_);                                   \
        xr[P][0][1] = *(const s16x8*)(xp_ + 1024);                            \
        xr[P][1][0] = *(const s16x8*)(xp_ + 2048);                            \
        xr[P][1][1] = *(const s16x8*)(xp_ + 3072); }

#define WSTAGE(S, E, KS) {                                                    \
        const char* ws_ = w1c + (((size_t)(E) * 25 + (KS)) << 14) + tid * 16; \
        char* wd_ = SLOT(S) + tid * 16;                                       \
        g2l16(ws_, wd_); g2l16(ws_ + 8192, wd_ + 8192); }

#define COMPUTE(S, P) {                                                       \
        const char* wb = SLOT(S) + nw * 8192 + lane * 16;                     \
        s16x8 wv[4][2];                                                       \
        _Pragma("unroll") for (int nt = 0; nt < 4; ++nt)                      \
            _Pragma("unroll") for (int kh = 0; kh < 2; ++kh)                  \
                wv[nt][kh] = *(const s16x8*)(wb + (nt * 2 + kh) * 1024);      \
        __builtin_amdgcn_s_setprio(1);                                        \
        _Pragma("unroll") for (int kh = 0; kh < 2; ++kh)                      \
            _Pragma("unroll") for (int nt = 0; nt < 4; ++nt)                  \
                _Pragma("unroll") for (int mt = 0; mt < 2; ++mt)              \
                    acc[nt][mt] = __builtin_amdgcn_mfma_f32_32x32x16_bf16(    \
                        wv[nt][kh], xr[P][mt][kh], acc[nt][mt], 0, 0, 0);     \
        __builtin_amdgcn_s_setprio(0); }

// counted-vmcnt sync wall: asm memory clobber also stops loads crossing.
#define RING_SYNC(VN) {                                                       \
        asm volatile("s_waitcnt vmcnt(" #VN ")" ::: "memory");                \
        __builtin_amdgcn_s_barrier();                                         \
        asm volatile("" ::: "memory"); }

// body at static position p (slot S = ks%3, parity P = p&1):
// issue x(ks+1) -> sched pin -> sync(6) -> compute -> stage w(ks+2)
#define BODY(S, P, KS) {                                                      \
        XPF((P) ^ 1, (KS) + 1)                                                \
        __builtin_amdgcn_sched_barrier(0);                                    \
        RING_SYNC(6)                                                          \
        COMPUTE(S, P)                                                         \
        { int wk_ = (KS) + 2; if (wk_ > 24) wk_ = 24;                         \
          WSTAGE(((S) + 2) % 3, e, wk_) } }

// ---------------- fused MoE kernel ----------------
// 256 blocks x 512 thr (8 waves, 1 block/CU, 2 waves/SIMD). Per expert:
// 256x256 layer-1 GEMM, K-step 32. W via 3-slot LDS ring (counted vmcnt,
// never 0 in loop); x DIRECT global->VGPR double-buffer (cuts LDS traffic
// 128->80 KB/step, below the 1033-cyc MFMA floor). T5 setprio on MFMA.
// mfma(W, x): D[n][m], m = lane&31, n = (r&3)+8*(r>>2)+4*(lane>>5).
__global__ void __launch_bounds__(512, 1)
moe_fused(const __bf16* __restrict__ xt, const float* __restrict__ b2g,
          const float* __restrict__ W3, const float* __restrict__ b3,
          const float* __restrict__ bg2, const __bf16* __restrict__ w1t,
          const __bf16* __restrict__ w2t, const __bf16* __restrict__ wg2t,
          float* __restrict__ out)
{
    extern __shared__ char lds[];
    char*  hb   = lds;                     // 64 KB, overlays W ring (epilogue only)
    float* expl = (float*)(lds + EXPL_OFF);
    float* b2s  = (float*)(lds + B2S_OFF);
    float* w3s  = (float*)(lds + W3S_OFF);
    float* b3s  = (float*)(lds + B3S_OFF);
    float* bg2s = (float*)(lds + BG2S_OFF);

    const int tid  = threadIdx.x;
    const int lane = tid & 63;
    const int wave = tid >> 6;             // 0..7
    const int rl   = lane & 31;
    const int hi   = lane >> 5;
    const int mw   = wave >> 1;            // 0..3 (64-row slice)
    const int nw   = wave & 1;             // 0..1 (128-col half)
    const int row0 = blockIdx.x * BM;
    const char* w1c = (const char*)w1t;
    const char* w2c = (const char*)w2t;
    const char* wgc = (const char*)wg2t;
    const char* xtc = (const char*)xt + ((size_t)blockIdx.x * 25 << 14);

    for (int i = tid; i < NEXP * NH2; i += 512) { b2s[i] = b2g[i]; w3s[i] = W3[i]; }
    if (tid < NEXP) { b3s[tid] = b3[tid]; bg2s[tid] = bg2[tid]; }
    __syncthreads();                       // drains vmcnt -> known 0

    f32x16 acc[4][2];                      // [nt][mt]
    f32x16 acc2[2];                        // layer-2 per jb (gate uses [0])
    s16x8  xr[2][2][2];                    // [parity][mt][kh]

    #pragma unroll 1
    for (int e = 0; e <= NEXP; ++e) {
        #pragma unroll
        for (int nt = 0; nt < 4; ++nt)
            #pragma unroll
            for (int mt = 0; mt < 2; ++mt)
                #pragma unroll
                for (int q = 0; q < 16; ++q) acc[nt][mt][q] = 0.f;
        #pragma unroll
        for (int q = 0; q < 16; ++q) { acc2[0][q] = 0.f; acc2[1][q] = 0.f; }

        // ---- prologue: w(0), x(0), w(1)  (8 vm ops outstanding) ----
        WSTAGE(0, e, 0)
        XPF(0, 0)
        WSTAGE(1, e, 1)

        // ---- K loop: 24 bodies via 4 x 6 static positions ----
        #pragma unroll 1
        for (int U = 0; U < 4; ++U) {
            const int k6 = 6 * U;
            BODY(0, 0, k6)
            BODY(1, 1, k6 + 1)
            BODY(2, 0, k6 + 2)
            BODY(0, 1, k6 + 3)
            BODY(1, 0, k6 + 4)
            BODY(2, 1, k6 + 5)
        }
        // peeled ks=24: slot 0, parity 0; full drain
        RING_SYNC(0)
        COMPUTE(0, 0)
        __syncthreads();                   // ring reads done; h may overlay

        // ---- epilogue: h in two 128-col halves through overlay buffer ----
        #pragma unroll
        for (int half = 0; half < 2; ++half) {
            if (nw == half) {
                #pragma unroll
                for (int mt = 0; mt < 2; ++mt)
                    #pragma unroll
                    for (int nt = 0; nt < 4; ++nt)
                        #pragma unroll
                        for (int q = 0; q < 4; ++q) {
                            uint2 wvv; short* p = (short*)&wvv;
                            #pragma unroll
                            for (int r2 = 0; r2 < 4; ++r2)
                                p[r2] = bf16b(fmaxf(acc[nt][mt][q * 4 + r2], 0.f));
                            *(uint2*)(hb + (((mw * 2 + mt) * 4 + nt) * 2 + (q >> 1)) * 1024
                                         + (rl + 32 * (q & 1)) * 16 + hi * 8) = wvv;
                        }
            }
            __syncthreads();               // h-half ready
            if (e < NEXP) {
                #pragma unroll
                for (int jb = 0; jb < 2; ++jb)
                    #pragma unroll
                    for (int k2 = 0; k2 < 4; ++k2)
                        #pragma unroll
                        for (int kh = 0; kh < 2; ++kh) {
                            s16x8 hf = *(const s16x8*)(hb + ((wave * 4 + k2) * 2 + kh) * 1024
                                                       + lane * 16);
                            s16x8 wf = *(const s16x8*)(w2c
                                + ((((size_t)e * 2 + jb) * 8 + half * 4 + k2) * 2 + kh) * 1024
                                + lane * 16);
                            acc2[jb] = __builtin_amdgcn_mfma_f32_32x32x16_bf16(
                                wf, hf, acc2[jb], 0, 0, 0);
                        }
            } else {
                #pragma unroll
                for (int k2 = 0; k2 < 4; ++k2)
                    #pragma unroll
                    for (int kh = 0; kh < 2; ++kh) {
                        s16x8 hf = *(const s16x8*)(hb + ((wave * 4 + k2) * 2 + kh) * 1024
                                                   + lane * 16);
                        s16x8 gf = *(const s16x8*)(wgc
                            + ((half * 4 + k2) * 2 + kh) * 1024 + lane * 16);
                        acc2[0] = __builtin_amdgcn_mfma_f32_32x32x16_bf16(
                            gf, hf, acc2[0], 0, 0, 0);
                    }
            }
            __syncthreads();               // reads done before next half / prologue
        }

        if (e < NEXP) {
            // ---- layer 3: lane m = wave*32+rl ----
            float part = 0.f;
            #pragma unroll
            for (int jb = 0; jb < 2; ++jb)
                #pragma unroll
                for (int q = 0; q < 4; ++q) {
                    f32x4 b2v = *(const f32x4*)(b2s + e * NH2 + jb * 32 + 8 * q + 4 * hi);
                    f32x4 w3v = *(const f32x4*)(w3s + e * NH2 + jb * 32 + 8 * q + 4 * hi);
                    #pragma unroll
                    for (int r2 = 0; r2 < 4; ++r2)
                        part += fmaxf(acc2[jb][q * 4 + r2] + b2v[r2], 0.f) * w3v[r2];
                }
            part += __shfl_xor(part, 32, 64);
            if (hi == 0)
                expl[(wave * 32 + rl) * NEXP + e] = part + b3s[e];
        } else {
            // ---- gate softmax + combine: lane m = wave*32+rl, j = r2+8q+4hi ----
            const int m = wave * 32 + rl;
            float lv[16], mx = -1e30f;
            #pragma unroll
            for (int q = 0; q < 4; ++q)
                #pragma unroll
                for (int r2 = 0; r2 < 4; ++r2) {
                    int j = r2 + 8 * q + 4 * hi;
                    int rg = q * 4 + r2;
                    lv[rg] = (j < NEXP) ? (acc2[0][rg] + bg2s[j]) : -1e30f;
                    mx = fmaxf(mx, lv[rg]);
                }
            mx = fmaxf(mx, __shfl_xor(mx, 32, 64));
            float s = 0.f, pv[16];
            #pragma unroll
            for (int rg = 0; rg < 16; ++rg) {
                pv[rg] = (lv[rg] > -1e29f) ? __expf(lv[rg] - mx) : 0.f;
                s += pv[rg];
            }
            s += __shfl_xor(s, 32, 64);
            const float inv = 1.f / s;
            #pragma unroll
            for (int q = 0; q < 4; ++q)
                #pragma unroll
                for (int r2 = 0; r2 < 4; ++r2) {
                    int j = r2 + 8 * q + 4 * hi;
                    if (j < NEXP) {
                        float g  = pv[q * 4 + r2] * inv;
                        float eo = expl[m * NEXP + j];
                        size_t o = (size_t)(row0 + m) * NEXP + j;
                        out[o] = g * eo;                        // output
                        out[(size_t)BTOT * NEXP + o] = g;       // gate_scores
                        out[(size_t)2 * BTOT * NEXP + o] = eo;  // expert_outputs
                    }
                }
        }
    }
}

extern "C" void kernel_launch(void* const* d_in, const int* in_sizes, int n_in,
                              void* d_out, int out_size, void* d_ws, size_t ws_size,
                              hipStream_t stream) {
    (void)in_sizes; (void)n_in; (void)out_size; (void)ws_size;
    const float* x   = (const float*)d_in[0];
    const float* W1  = (const float*)d_in[1];
    const float* b1  = (const float*)d_in[2];
    const float* W2  = (const float*)d_in[3];
    const float* b2  = (const float*)d_in[4];
    const float* W3  = (const float*)d_in[5];
    const float* b3  = (const float*)d_in[6];
    const float* Wg1 = (const float*)d_in[7];
    const float* bg1 = (const float*)d_in[8];
    const float* Wg2 = (const float*)d_in[9];
    const float* bg2 = (const float*)d_in[10];

    // ws layout (bf16): w1t 11*25*8192 | w2t 20480*8 | wg2t 1024*8 | xt [256][25][8192]
    __bf16* w1t  = (__bf16*)d_ws;
    __bf16* w2t  = w1t + (size_t)11 * 25 * 8192;
    __bf16* wg2t = w2t + (size_t)20480 * 8;
    __bf16* xt   = wg2t + (size_t)1024 * 8;

    hipFuncSetAttribute((const void*)moe_fused,
                        hipFuncAttributeMaxDynamicSharedMemorySize, LDS_TOTAL);

    prep_w1<<<1100, 256, 0, stream>>>(W1, b1, Wg1, bg1, w1t);
    prep_w2<<<80, 256, 0, stream>>>(W2, w2t);
    prep_wg2<<<4, 256, 0, stream>>>(Wg2, wg2t);
    prep_x<<<2048, 256, 0, stream>>>(x, xt);
    moe_fused<<<BTOT / BM, 512, LDS_TOTAL, stream>>>(
        xt, b2, W3, b3, bg2, w1t, w2t, wg2t, (float*)d_out);
}

// Round 15
// 393.815 us; speedup vs baseline: 1.0529x; 1.0529x over previous
//
#include <hip/hip_runtime.h>
#include <hip/hip_bf16.h>
#include <stdint.h>

// ---------------- problem dims ----------------
#define BTOT   65536
#define DIN    784
#define NH1    256
#define NH2    64
#define NEXP   10
#define BM     256
#define NKS1   25      // K1 = 800 (784 + bias row @784 + zeros), 25 steps of 32

// ---------------- LDS layout (bytes) ----------------
// 3-slot staging ring, 32 KB each: slot s = lds + s*32768 (x 16K | w 16K).
// h (64 KB) OVERLAYS slots 0-1 (used only after the K-loop fully drains).
#define SLOT(s)   (lds + (s) * 32768)
#define EXPL_OFF  98304                    // [256 m][10 e] f32 = 10240
#define B2S_OFF   108544                   // [10][64] f32 = 2560
#define W3S_OFF   111104                   // [10][64] f32 = 2560
#define B3S_OFF   113664                   // 64
#define BG2S_OFF  113728                   // 64
#define LDS_TOTAL 113792

typedef short s16x8  __attribute__((ext_vector_type(8)));
typedef float f32x4  __attribute__((ext_vector_type(4)));
typedef float f32x16 __attribute__((ext_vector_type(16)));

__device__ __forceinline__ short bf16b(float v) {
    __bf16 b = (__bf16)v;
    return __builtin_bit_cast(short, b);
}

__device__ __forceinline__ void g2l16(const void* g, void* l) {
    __builtin_amdgcn_global_load_lds(
        (const __attribute__((address_space(1))) unsigned char*)g,
        (__attribute__((address_space(3))) unsigned char*)l, 16, 0, 0);
}

// ---------------- prep: fragment-order weights (bf16, b1 folded) ------------
// w1t [e11][ks25][nb8][kh2][lane64][8]: n=nb*32+(lane&31),
// k=ks*32+kh*16+(lane>>5)*8+j; k==784 -> bias; e==10 -> gate Wg1/bg1.
__global__ void prep_w1(const float* __restrict__ W1, const float* __restrict__ b1,
                        const float* __restrict__ Wg1, const float* __restrict__ bg1,
                        __bf16* __restrict__ dst) {
    int t = blockIdx.x * 256 + threadIdx.x;          // < 281600
    int lane = t & 63;
    int kh = (t >> 6) & 1;
    int nb = (t >> 7) & 7;
    int r  = t >> 10;
    int ks = r % 25, e = r / 25;
    int n  = nb * 32 + (lane & 31);
    int k0 = ks * 32 + kh * 16 + (lane >> 5) * 8;
    const float* src  = (e < NEXP) ? (W1 + (size_t)e * DIN * NH1) : Wg1;
    const float* bias = (e < NEXP) ? (b1 + e * NH1) : bg1;
    s16x8 o;
    #pragma unroll
    for (int j = 0; j < 8; ++j) {
        int k = k0 + j;
        float v = (k < DIN) ? src[(size_t)k * NH1 + n]
                            : ((k == DIN) ? bias[n] : 0.f);
        o[j] = bf16b(v);
    }
    *(s16x8*)((short*)dst + (size_t)t * 8) = o;
}

// w2t [e10][jb2][ks8][kh2][lane64][8]: n=jb*32+(lane&31), K2=256.
__global__ void prep_w2(const float* __restrict__ W2, __bf16* __restrict__ dst) {
    int t = blockIdx.x * 256 + threadIdx.x;          // < 20480
    int lane = t & 63;
    int kh = (t >> 6) & 1;
    int ks = (t >> 7) & 7;
    int jb = (t >> 10) & 1;
    int e  = t >> 11;
    int n  = jb * 32 + (lane & 31);
    int k0 = ks * 32 + kh * 16 + (lane >> 5) * 8;
    s16x8 o;
    #pragma unroll
    for (int j = 0; j < 8; ++j)
        o[j] = bf16b(W2[((size_t)e * NH1 + k0 + j) * NH2 + n]);
    *(s16x8*)((short*)dst + (size_t)t * 8) = o;
}

// wg2t [ks8][kh2][lane64][8]: col = lane&31 (valid <10), K2=256.
__global__ void prep_wg2(const float* __restrict__ Wg2, __bf16* __restrict__ dst) {
    int t = blockIdx.x * 256 + threadIdx.x;
    if (t >= 1024) return;
    int lane = t & 63;
    int kh = (t >> 6) & 1;
    int ks = t >> 7;
    int n  = lane & 31;
    int k0 = ks * 32 + kh * 16 + (lane >> 5) * 8;
    s16x8 o;
    #pragma unroll
    for (int j = 0; j < 8; ++j)
        o[j] = bf16b((n < NEXP) ? Wg2[(size_t)(k0 + j) * NEXP + n] : 0.f);
    *(s16x8*)((short*)dst + (size_t)t * 8) = o;
}

// ---- staging + body macros ----
#define STAGE(S, E, KS) {                                                     \
        const char* xs_ = xtc + ((size_t)(KS) << 14) + tid * 16;              \
        char* xd_ = SLOT(S) + tid * 16;                                       \
        g2l16(xs_, xd_); g2l16(xs_ + 8192, xd_ + 8192);                       \
        const char* ws_ = w1c + (((size_t)(E) * 25 + (KS)) << 14) + tid * 16; \
        char* wd_ = SLOT(S) + 16384 + tid * 16;                               \
        g2l16(ws_, wd_); g2l16(ws_ + 8192, wd_ + 8192); }

// w-only stage (e=0 path)
#define WSTAGE1(S, KS) {                                                      \
        const char* ws_ = w1c + ((size_t)(KS) << 14) + tid * 16;              \
        char* wd_ = SLOT(S) + 16384 + tid * 16;                               \
        g2l16(ws_, wd_); g2l16(ws_ + 8192, wd_ + 8192); }

// e=0: load 16 fp32 of x (row xrow, k-half xkh) into xf; ks=24 upper half is
// the bias-1 + zero pad (k=784..799).
#define XLOAD(KS) { if ((KS) < 24 || xkh == 0) {                              \
            _Pragma("unroll") for (int i4 = 0; i4 < 4; ++i4)                  \
                *(float4*)(xf + 4 * i4) =                                     \
                    *(const float4*)(xrp + (KS) * 32 + 4 * i4);               \
        } else { _Pragma("unroll") for (int i4 = 0; i4 < 16; ++i4)            \
                     xf[i4] = 0.f;                                            \
                 xf[0] = 1.f; } }

// e=0: convert + write to LDS slot x-region AND write-through to xt (global)
#define XWRITE(B, KS) { s16x8 l8, h8;                                         \
        _Pragma("unroll") for (int j = 0; j < 8; ++j) {                       \
            l8[j] = bf16b(xf[j]); h8[j] = bf16b(xf[8 + j]); }                 \
        *(s16x8*)(SLOT(B) + xoff)       = l8;                                 \
        *(s16x8*)(SLOT(B) + xoff + 512) = h8;                                 \
        char* xg_ = xtw + ((size_t)(KS) << 14) + xoff;                        \
        *(s16x8*)xg_ = l8; *(s16x8*)(xg_ + 512) = h8; }

#define COMPUTE(S) {                                                          \
        const char* ab = SLOT(S) + mw * 4096 + lane * 16;                     \
        const char* wb = SLOT(S) + 16384 + nw * 8192 + lane * 16;             \
        s16x8 xv[2][2], wv[4][2];                                             \
        _Pragma("unroll") for (int mt = 0; mt < 2; ++mt)                      \
            _Pragma("unroll") for (int kh = 0; kh < 2; ++kh)                  \
                xv[mt][kh] = *(const s16x8*)(ab + (mt * 2 + kh) * 1024);      \
        _Pragma("unroll") for (int nt = 0; nt < 4; ++nt)                      \
            _Pragma("unroll") for (int kh = 0; kh < 2; ++kh)                  \
                wv[nt][kh] = *(const s16x8*)(wb + (nt * 2 + kh) * 1024);      \
        __builtin_amdgcn_s_setprio(1);                                        \
        _Pragma("unroll") for (int kh = 0; kh < 2; ++kh)                      \
            _Pragma("unroll") for (int nt = 0; nt < 4; ++nt)                  \
                _Pragma("unroll") for (int mt = 0; mt < 2; ++mt)              \
                    acc[nt][mt] = __builtin_amdgcn_mfma_f32_32x32x16_bf16(    \
                        wv[nt][kh], xv[mt][kh], acc[nt][mt], 0, 0, 0);        \
        __builtin_amdgcn_s_setprio(0); }

// counted-vmcnt sync wall
#define RING_SYNC(VN) {                                                       \
        asm volatile("s_waitcnt vmcnt(" #VN ")" ::: "memory");                \
        __builtin_amdgcn_s_barrier();                                         \
        asm volatile("" ::: "memory"); }

// ring body: sync -> ds_reads -> stage(ks+2) issue (hides under MFMA) -> MFMA
#define BODY(S, KS) {                                                         \
        RING_SYNC(4)                                                          \
        const char* ab = SLOT(S) + mw * 4096 + lane * 16;                     \
        const char* wb = SLOT(S) + 16384 + nw * 8192 + lane * 16;             \
        s16x8 xv[2][2], wv[4][2];                                             \
        _Pragma("unroll") for (int mt = 0; mt < 2; ++mt)                      \
            _Pragma("unroll") for (int kh = 0; kh < 2; ++kh)                  \
                xv[mt][kh] = *(const s16x8*)(ab + (mt * 2 + kh) * 1024);      \
        _Pragma("unroll") for (int nt = 0; nt < 4; ++nt)                      \
            _Pragma("unroll") for (int kh = 0; kh < 2; ++kh)                  \
                wv[nt][kh] = *(const s16x8*)(wb + (nt * 2 + kh) * 1024);      \
        { int wk_ = (KS) + 2; if (wk_ > 24) wk_ = 24;                         \
          STAGE(((S) + 2) % 3, e, wk_) }                                      \
        __builtin_amdgcn_s_setprio(1);                                        \
        _Pragma("unroll") for (int kh = 0; kh < 2; ++kh)                      \
            _Pragma("unroll") for (int nt = 0; nt < 4; ++nt)                  \
                _Pragma("unroll") for (int mt = 0; mt < 2; ++mt)              \
                    acc[nt][mt] = __builtin_amdgcn_mfma_f32_32x32x16_bf16(    \
                        wv[nt][kh], xv[mt][kh], acc[nt][mt], 0, 0, 0);        \
        __builtin_amdgcn_s_setprio(0); }

// ---------------- fused MoE kernel ----------------
// 256 blocks x 512 thr (8 waves, 1 block/CU, 2 waves/SIMD; waves_per_eu(2,2)
// pins the 256-VGPR budget -> no scratch spill, r13's silent 18MB/dispatch).
// e=0: 2-phase loop converts x fp32->bf16 (reg-staged) into LDS AND writes
// fragment-order xt to ws (fuses prep_x). e>=1 + gate: r13's 3-slot counted-
// vmcnt ring (never 0 in loop), stage issued before the MFMA cluster, T5
// setprio. mfma(W, x): D[n][m], m = lane&31, n = (r&3)+8*(r>>2)+4*(lane>>5).
__global__ void __launch_bounds__(512)
__attribute__((amdgpu_waves_per_eu(2, 2)))
moe_fused(const float* __restrict__ x, __bf16* __restrict__ xt,
          const float* __restrict__ b2g, const float* __restrict__ W3,
          const float* __restrict__ b3, const float* __restrict__ bg2,
          const __bf16* __restrict__ w1t, const __bf16* __restrict__ w2t,
          const __bf16* __restrict__ wg2t, float* __restrict__ out)
{
    extern __shared__ char lds[];
    char*  hb   = lds;                     // overlays slots 0-1 (epilogue only)
    float* expl = (float*)(lds + EXPL_OFF);
    float* b2s  = (float*)(lds + B2S_OFF);
    float* w3s  = (float*)(lds + W3S_OFF);
    float* b3s  = (float*)(lds + B3S_OFF);
    float* bg2s = (float*)(lds + BG2S_OFF);

    const int tid  = threadIdx.x;
    const int lane = tid & 63;
    const int wave = tid >> 6;             // 0..7
    const int rl   = lane & 31;
    const int hi   = lane >> 5;
    const int mw   = wave >> 1;            // 0..3 (64-row slice)
    const int nw   = wave & 1;             // 0..1 (128-col half)
    const int row0 = blockIdx.x * BM;
    const char* w1c = (const char*)w1t;
    const char* w2c = (const char*)w2t;
    const char* wgc = (const char*)wg2t;
    const char* xtc = (const char*)xt + ((size_t)blockIdx.x * 25 << 14);
    char*       xtw = (char*)xt + ((size_t)blockIdx.x * 25 << 14);

    // e=0 x-staging coords: thread -> (row, k-half)
    const int xrow = tid >> 1, xkh = tid & 1;
    const float* xrp = x + (size_t)(row0 + xrow) * DIN + xkh * 16;
    const int xoff = ((xrow >> 5) * 2 + xkh) * 1024 + (xrow & 31) * 16;
    float xf[16];

    for (int i = tid; i < NEXP * NH2; i += 512) { b2s[i] = b2g[i]; w3s[i] = W3[i]; }
    if (tid < NEXP) { b3s[tid] = b3[tid]; bg2s[tid] = bg2[tid]; }
    __syncthreads();                       // drains vmcnt -> known 0

    f32x16 acc[4][2];                      // [nt][mt]
    f32x16 acc2[2];                        // layer-2 per jb (gate uses [0])

    #pragma unroll 1
    for (int e = 0; e <= NEXP; ++e) {
        #pragma unroll
        for (int nt = 0; nt < 4; ++nt)
            #pragma unroll
            for (int mt = 0; mt < 2; ++mt)
                #pragma unroll
                for (int q = 0; q < 16; ++q) acc[nt][mt][q] = 0.f;
        #pragma unroll
        for (int q = 0; q < 16; ++q) { acc2[0][q] = 0.f; acc2[1][q] = 0.f; }

        if (e == 0) {
            // ---- e=0: 2-phase dbuf (slots 0/1), x fp32->bf16 + xt write ----
            int cur = 0;
            XLOAD(0)
            WSTAGE1(0, 0)
            XWRITE(0, 0)
            __syncthreads();
            #pragma unroll 1
            for (int ks = 0; ks < NKS1; ++ks) {
                if (ks < 24) { XLOAD(ks + 1) WSTAGE1(cur ^ 1, ks + 1) }
                COMPUTE(cur)
                if (ks < 24) XWRITE(cur ^ 1, ks + 1)
                __syncthreads();
                cur ^= 1;
            }
        } else {
            // ---- e>=1 / gate: 3-slot counted-vmcnt ring ----
            STAGE(0, e, 0)
            STAGE(1, e, 1)
            #pragma unroll 1
            for (int T = 0; T < 8; ++T) {
                const int t3 = 3 * T;
                BODY(0, t3)
                BODY(1, t3 + 1)
                BODY(2, t3 + 2)
            }
            RING_SYNC(0)
            COMPUTE(0)                     // peeled ks=24 (slot 0)
            __syncthreads();               // ring reads done; h may overlay
        }

        // ---- epilogue: h in two 128-col halves through overlay buffer ----
        #pragma unroll
        for (int half = 0; half < 2; ++half) {
            if (nw == half) {
                #pragma unroll
                for (int mt = 0; mt < 2; ++mt)
                    #pragma unroll
                    for (int nt = 0; nt < 4; ++nt)
                        #pragma unroll
                        for (int q = 0; q < 4; ++q) {
                            uint2 wvv; short* p = (short*)&wvv;
                            #pragma unroll
                            for (int r2 = 0; r2 < 4; ++r2)
                                p[r2] = bf16b(fmaxf(acc[nt][mt][q * 4 + r2], 0.f));
                            *(uint2*)(hb + (((mw * 2 + mt) * 4 + nt) * 2 + (q >> 1)) * 1024
                                         + (rl + 32 * (q & 1)) * 16 + hi * 8) = wvv;
                        }
            }
            __syncthreads();               // h-half ready
            if (e < NEXP) {
                #pragma unroll
                for (int jb = 0; jb < 2; ++jb)
                    #pragma unroll
                    for (int k2 = 0; k2 < 4; ++k2)
                        #pragma unroll
                        for (int kh = 0; kh < 2; ++kh) {
                            s16x8 hf = *(const s16x8*)(hb + ((wave * 4 + k2) * 2 + kh) * 1024
                                                       + lane * 16);
                            s16x8 wf = *(const s16x8*)(w2c
                                + ((((size_t)e * 2 + jb) * 8 + half * 4 + k2) * 2 + kh) * 1024
                                + lane * 16);
                            acc2[jb] = __builtin_amdgcn_mfma_f32_32x32x16_bf16(
                                wf, hf, acc2[jb], 0, 0, 0);
                        }
            } else {
                #pragma unroll
                for (int k2 = 0; k2 < 4; ++k2)
                    #pragma unroll
                    for (int kh = 0; kh < 2; ++kh) {
                        s16x8 hf = *(const s16x8*)(hb + ((wave * 4 + k2) * 2 + kh) * 1024
                                                   + lane * 16);
                        s16x8 gf = *(const s16x8*)(wgc
                            + ((half * 4 + k2) * 2 + kh) * 1024 + lane * 16);
                        acc2[0] = __builtin_amdgcn_mfma_f32_32x32x16_bf16(
                            gf, hf, acc2[0], 0, 0, 0);
                    }
            }
            __syncthreads();               // reads done before next half / prologue
        }

        if (e < NEXP) {
            // ---- layer 3: lane m = wave*32+rl ----
            float part = 0.f;
            #pragma unroll
            for (int jb = 0; jb < 2; ++jb)
                #pragma unroll
                for (int q = 0; q < 4; ++q) {
                    f32x4 b2v = *(const f32x4*)(b2s + e * NH2 + jb * 32 + 8 * q + 4 * hi);
                    f32x4 w3v = *(const f32x4*)(w3s + e * NH2 + jb * 32 + 8 * q + 4 * hi);
                    #pragma unroll
                    for (int r2 = 0; r2 < 4; ++r2)
                        part += fmaxf(acc2[jb][q * 4 + r2] + b2v[r2], 0.f) * w3v[r2];
                }
            part += __shfl_xor(part, 32, 64);
            if (hi == 0)
                expl[(wave * 32 + rl) * NEXP + e] = part + b3s[e];
        } else {
            // ---- gate softmax + combine: lane m = wave*32+rl, j = r2+8q+4hi ----
            const int m = wave * 32 + rl;
            float lv[16], mx = -1e30f;
            #pragma unroll
            for (int q = 0; q < 4; ++q)
                #pragma unroll
                for (int r2 = 0; r2 < 4; ++r2) {
                    int j = r2 + 8 * q + 4 * hi;
                    int rg = q * 4 + r2;
                    lv[rg] = (j < NEXP) ? (acc2[0][rg] + bg2s[j]) : -1e30f;
                    mx = fmaxf(mx, lv[rg]);
                }
            mx = fmaxf(mx, __shfl_xor(mx, 32, 64));
            float s = 0.f, pv[16];
            #pragma unroll
            for (int rg = 0; rg < 16; ++rg) {
                pv[rg] = (lv[rg] > -1e29f) ? __expf(lv[rg] - mx) : 0.f;
                s += pv[rg];
            }
            s += __shfl_xor(s, 32, 64);
            const float inv = 1.f / s;
            #pragma unroll
            for (int q = 0; q < 4; ++q)
                #pragma unroll
                for (int r2 = 0; r2 < 4; ++r2) {
                    int j = r2 + 8 * q + 4 * hi;
                    if (j < NEXP) {
                        float g  = pv[q * 4 + r2] * inv;
                        float eo = expl[m * NEXP + j];
                        size_t o = (size_t)(row0 + m) * NEXP + j;
                        out[o] = g * eo;                        // output
                        out[(size_t)BTOT * NEXP + o] = g;       // gate_scores
                        out[(size_t)2 * BTOT * NEXP + o] = eo;  // expert_outputs
                    }
                }
        }
    }
}

extern "C" void kernel_launch(void* const* d_in, const int* in_sizes, int n_in,
                              void* d_out, int out_size, void* d_ws, size_t ws_size,
                              hipStream_t stream) {
    (void)in_sizes; (void)n_in; (void)out_size; (void)ws_size;
    const float* x   = (const float*)d_in[0];
    const float* W1  = (const float*)d_in[1];
    const float* b1  = (const float*)d_in[2];
    const float* W2  = (const float*)d_in[3];
    const float* b2  = (const float*)d_in[4];
    const float* W3  = (const float*)d_in[5];
    const float* b3  = (const float*)d_in[6];
    const float* Wg1 = (const float*)d_in[7];
    const float* bg1 = (const float*)d_in[8];
    const float* Wg2 = (const float*)d_in[9];
    const float* bg2 = (const float*)d_in[10];

    // ws layout (bf16): w1t 11*25*8192 | w2t 20480*8 | wg2t 1024*8 | xt [256][25][8192]
    __bf16* w1t  = (__bf16*)d_ws;
    __bf16* w2t  = w1t + (size_t)11 * 25 * 8192;
    __bf16* wg2t = w2t + (size_t)20480 * 8;
    __bf16* xt   = wg2t + (size_t)1024 * 8;

    hipFuncSetAttribute((const void*)moe_fused,
                        hipFuncAttributeMaxDynamicSharedMemorySize, LDS_TOTAL);

    prep_w1<<<1100, 256, 0, stream>>>(W1, b1, Wg1, bg1, w1t);
    prep_w2<<<80, 256, 0, stream>>>(W2, w2t);
    prep_wg2<<<4, 256, 0, stream>>>(Wg2, wg2t);
    moe_fused<<<BTOT / BM, 512, LDS_TOTAL, stream>>>(
        x, xt, b2, W3, b3, bg2, w1t, w2t, wg2t, (float*)d_out);
}

// Round 16
// 347.948 us; speedup vs baseline: 1.1917x; 1.1318x over previous
//
#include <hip/hip_runtime.h>
#include <hip/hip_bf16.h>
#include <stdint.h>

// ---------------- problem dims ----------------
#define BTOT   65536
#define DIN    784
#define NH1    256
#define NH2    64
#define NEXP   10
#define BM     256
#define NKS1   25      // K1 = 800 (784 + bias row @784 + zeros), 25 steps of 32

// ---------------- LDS layout (bytes) ----------------
// 4-slot staging ring, 32 KB each (x 16K | w 16K). h (128 KB, FULL) overlays
// the whole ring — used only after the K-loop fully drains. This kills the
// acc/acc2 lifetime overlap that spilled r13 (~18 MB/dispatch scratch).
#define SLOT(s)   (lds + (s) * 32768)
#define EXPL_OFF  131072                   // [256 m][10 e] f32 = 10240
#define B2S_OFF   141312                   // [10][64] f32 = 2560
#define W3S_OFF   143872                   // [10][64] f32 = 2560
#define B3S_OFF   146432                   // 64
#define BG2S_OFF  146496                   // 64
#define LDS_TOTAL 146560

typedef short s16x8  __attribute__((ext_vector_type(8)));
typedef float f32x4  __attribute__((ext_vector_type(4)));
typedef float f32x16 __attribute__((ext_vector_type(16)));

__device__ __forceinline__ short bf16b(float v) {
    __bf16 b = (__bf16)v;
    return __builtin_bit_cast(short, b);
}

__device__ __forceinline__ void g2l16(const void* g, void* l) {
    __builtin_amdgcn_global_load_lds(
        (const __attribute__((address_space(1))) unsigned char*)g,
        (__attribute__((address_space(3))) unsigned char*)l, 16, 0, 0);
}

// ---------------- prep: fragment-order weights (bf16, b1 folded) ------------
// w1t [e11][ks25][nb8][kh2][lane64][8]: n=nb*32+(lane&31),
// k=ks*32+kh*16+(lane>>5)*8+j; k==784 -> bias; e==10 -> gate Wg1/bg1.
__global__ void prep_w1(const float* __restrict__ W1, const float* __restrict__ b1,
                        const float* __restrict__ Wg1, const float* __restrict__ bg1,
                        __bf16* __restrict__ dst) {
    int t = blockIdx.x * 256 + threadIdx.x;          // < 281600
    int lane = t & 63;
    int kh = (t >> 6) & 1;
    int nb = (t >> 7) & 7;
    int r  = t >> 10;
    int ks = r % 25, e = r / 25;
    int n  = nb * 32 + (lane & 31);
    int k0 = ks * 32 + kh * 16 + (lane >> 5) * 8;
    const float* src  = (e < NEXP) ? (W1 + (size_t)e * DIN * NH1) : Wg1;
    const float* bias = (e < NEXP) ? (b1 + e * NH1) : bg1;
    s16x8 o;
    #pragma unroll
    for (int j = 0; j < 8; ++j) {
        int k = k0 + j;
        float v = (k < DIN) ? src[(size_t)k * NH1 + n]
                            : ((k == DIN) ? bias[n] : 0.f);
        o[j] = bf16b(v);
    }
    *(s16x8*)((short*)dst + (size_t)t * 8) = o;
}

// w2t [e10][jb2][ks8][kh2][lane64][8]: n=jb*32+(lane&31), K2=256.
__global__ void prep_w2(const float* __restrict__ W2, __bf16* __restrict__ dst) {
    int t = blockIdx.x * 256 + threadIdx.x;          // < 20480
    int lane = t & 63;
    int kh = (t >> 6) & 1;
    int ks = (t >> 7) & 7;
    int jb = (t >> 10) & 1;
    int e  = t >> 11;
    int n  = jb * 32 + (lane & 31);
    int k0 = ks * 32 + kh * 16 + (lane >> 5) * 8;
    s16x8 o;
    #pragma unroll
    for (int j = 0; j < 8; ++j)
        o[j] = bf16b(W2[((size_t)e * NH1 + k0 + j) * NH2 + n]);
    *(s16x8*)((short*)dst + (size_t)t * 8) = o;
}

// wg2t [ks8][kh2][lane64][8]: col = lane&31 (valid <10), K2=256.
__global__ void prep_wg2(const float* __restrict__ Wg2, __bf16* __restrict__ dst) {
    int t = blockIdx.x * 256 + threadIdx.x;
    if (t >= 1024) return;
    int lane = t & 63;
    int kh = (t >> 6) & 1;
    int ks = t >> 7;
    int n  = lane & 31;
    int k0 = ks * 32 + kh * 16 + (lane >> 5) * 8;
    s16x8 o;
    #pragma unroll
    for (int j = 0; j < 8; ++j)
        o[j] = bf16b((n < NEXP) ? Wg2[(size_t)(k0 + j) * NEXP + n] : 0.f);
    *(s16x8*)((short*)dst + (size_t)t * 8) = o;
}

// prep_x: x fp32 -> bf16 fragment-order [rb256][ks25][mq8][kh2][hw2][row32][j8]
__global__ void prep_x(const float* __restrict__ x, __bf16* __restrict__ dst) {
    __shared__ short xl[32 * 800];
    const int rb = blockIdx.x >> 3, mq = blockIdx.x & 7;
    const int tid = threadIdx.x;
    const float* xg = x + ((size_t)rb * 256 + mq * 32) * DIN;
    #pragma unroll 4
    for (int i = 0; i < 25; ++i) {                   // 32*196 = 6272 float4
        int idx = tid + i * 256;
        if (idx < 6272) {
            int r = idx / 196, c = (idx % 196) * 4;
            float4 v = *(const float4*)(xg + (size_t)r * DIN + c);
            uint2 w; short* p = (short*)&w;
            p[0] = bf16b(v.x); p[1] = bf16b(v.y);
            p[2] = bf16b(v.z); p[3] = bf16b(v.w);
            *(uint2*)(xl + r * 800 + c) = w;
        }
    }
    for (int i = tid; i < 32 * 16; i += 256) {       // k=784 bias-1, 785..799 zeros
        int r = i >> 4, k = DIN + (i & 15);
        xl[r * 800 + k] = (k == DIN) ? bf16b(1.f) : (short)0;
    }
    __syncthreads();
    #pragma unroll 2
    for (int i = 0; i < 13; ++i) {                   // 3200 x 16B chunks
        int idx = tid + i * 256;
        if (idx < 3200) {
            int row = idx & 31, c8 = idx >> 5;       // c8 in [0,100)
            int ks = c8 >> 2, rem = c8 & 3;
            int kh = rem >> 1, hw = rem & 1;
            s16x8 v = *(const s16x8*)(xl + row * 800 + ks * 32 + kh * 16 + hw * 8);
            *(s16x8*)((char*)dst + (((size_t)(rb * 25 + ks) * 8 + mq) * 2048)
                      + kh * 1024 + hw * 512 + row * 16) = v;
        }
    }
}

// ---- staging + body macros ----
#define STAGE(S, E, KS) {                                                     \
        const char* xs_ = xtc + ((size_t)(KS) << 14) + tid * 16;              \
        char* xd_ = SLOT(S) + tid * 16;                                       \
        g2l16(xs_, xd_); g2l16(xs_ + 8192, xd_ + 8192);                       \
        const char* ws_ = w1c + (((size_t)(E) * 25 + (KS)) << 14) + tid * 16; \
        char* wd_ = SLOT(S) + 16384 + tid * 16;                               \
        g2l16(ws_, wd_); g2l16(ws_ + 8192, wd_ + 8192); }

#define COMPUTE(S) {                                                          \
        const char* ab = SLOT(S) + mw * 4096 + lane * 16;                     \
        const char* wb = SLOT(S) + 16384 + nw * 8192 + lane * 16;             \
        s16x8 xv[2][2], wv[4][2];                                             \
        _Pragma("unroll") for (int mt = 0; mt < 2; ++mt)                      \
            _Pragma("unroll") for (int kh = 0; kh < 2; ++kh)                  \
                xv[mt][kh] = *(const s16x8*)(ab + (mt * 2 + kh) * 1024);      \
        _Pragma("unroll") for (int nt = 0; nt < 4; ++nt)                      \
            _Pragma("unroll") for (int kh = 0; kh < 2; ++kh)                  \
                wv[nt][kh] = *(const s16x8*)(wb + (nt * 2 + kh) * 1024);      \
        _Pragma("unroll") for (int kh = 0; kh < 2; ++kh)                      \
            _Pragma("unroll") for (int nt = 0; nt < 4; ++nt)                  \
                _Pragma("unroll") for (int mt = 0; mt < 2; ++mt)              \
                    acc[nt][mt] = __builtin_amdgcn_mfma_f32_32x32x16_bf16(    \
                        wv[nt][kh], xv[mt][kh], acc[nt][mt], 0, 0, 0); }

// counted-vmcnt sync wall
#define RING_SYNC(VN) {                                                       \
        asm volatile("s_waitcnt vmcnt(" #VN ")" ::: "memory");                \
        __builtin_amdgcn_s_barrier();                                         \
        asm volatile("" ::: "memory"); }

// ring body (steady state): wait own stage (oldest 4 of 12 outstanding),
// barrier, compute, stage ks+3 into the slot read one body ago (WAR-safe:
// that read completed before this body's barrier).
#define BODY(S, KS) {                                                         \
        RING_SYNC(8)                                                          \
        COMPUTE(S)                                                            \
        STAGE(((S) + 3) & 3, e, (KS) + 3) }

// ---------------- fused MoE kernel ----------------
// 256 blocks x 512 thr (8 waves, 1 block/CU, 2 waves/SIMD). Per expert:
// 256x256 layer-1 GEMM, K-step 32, 4-slot LDS ring, depth-3 prefetch with
// COUNTED vmcnt (never 0 until the tail) -> ~1500 cyc in flight covers the
// ~900-cyc HBM misses on xt. h written FULL (ring overlay) so acc dies
// before acc2 is born -> peak regs < 256, no scratch spill (r13's WRITE=25MB).
// mfma(W, x): D[n][m], m = lane&31, n = (r&3)+8*(r>>2)+4*(lane>>5).
__global__ void __launch_bounds__(512)
__attribute__((amdgpu_waves_per_eu(2, 2)))
moe_fused(const __bf16* __restrict__ xt, const float* __restrict__ b2g,
          const float* __restrict__ W3, const float* __restrict__ b3,
          const float* __restrict__ bg2, const __bf16* __restrict__ w1t,
          const __bf16* __restrict__ w2t, const __bf16* __restrict__ wg2t,
          float* __restrict__ out)
{
    extern __shared__ char lds[];
    char*  hb   = lds;                     // FULL h: [mtile8][ks2_8][kh2][1024B]
    float* expl = (float*)(lds + EXPL_OFF);
    float* b2s  = (float*)(lds + B2S_OFF);
    float* w3s  = (float*)(lds + W3S_OFF);
    float* b3s  = (float*)(lds + B3S_OFF);
    float* bg2s = (float*)(lds + BG2S_OFF);

    const int tid  = threadIdx.x;
    const int lane = tid & 63;
    const int wave = tid >> 6;             // 0..7
    const int rl   = lane & 31;
    const int hi   = lane >> 5;
    const int mw   = wave >> 1;            // 0..3 (64-row slice)
    const int nw   = wave & 1;             // 0..1 (128-col half)
    const int row0 = blockIdx.x * BM;
    const char* w1c = (const char*)w1t;
    const char* w2c = (const char*)w2t;
    const char* wgc = (const char*)wg2t;
    const char* xtc = (const char*)xt + ((size_t)blockIdx.x * 25 << 14);

    for (int i = tid; i < NEXP * NH2; i += 512) { b2s[i] = b2g[i]; w3s[i] = W3[i]; }
    if (tid < NEXP) { b3s[tid] = b3[tid]; bg2s[tid] = bg2[tid]; }
    __syncthreads();                       // drains vmcnt -> known 0

    f32x16 acc[4][2];                      // [nt][mt] (layer-1)

    #pragma unroll 1
    for (int e = 0; e <= NEXP; ++e) {
        #pragma unroll
        for (int nt = 0; nt < 4; ++nt)
            #pragma unroll
            for (int mt = 0; mt < 2; ++mt)
                #pragma unroll
                for (int q = 0; q < 16; ++q) acc[nt][mt][q] = 0.f;

        // ---- prologue: stage ks=0,1,2 (12 vm ops outstanding) ----
        STAGE(0, e, 0)
        STAGE(1, e, 1)
        STAGE(2, e, 2)

        // ---- K loop: bodies 0..19 (5 x 4 slots), then peeled tail ----
        #pragma unroll 1
        for (int T = 0; T < 5; ++T) {
            const int k4 = 4 * T;
            BODY(0, k4)
            BODY(1, k4 + 1)
            BODY(2, k4 + 2)
            BODY(3, k4 + 3)
        }
        BODY(0, 20)                        // stages ks=23 -> slot 3
        BODY(1, 21)                        // stages ks=24 -> slot 0
        RING_SYNC(8)  COMPUTE(2)           // ks=22 (no stage)
        RING_SYNC(4)  COMPUTE(3)           // ks=23
        RING_SYNC(0)  COMPUTE(0)           // ks=24
        __syncthreads();                   // all ring reads done; h may overlay

        // ---- h-write (FULL): value (nt,mt,q,r2) ->
        //      h[m=(mw*2+mt)*32+rl][n=nw*128+nt*32+(r2+8q+4hi)]
        //      block (mtile=mw*2+mt, ks2=nw*4+nt, kh2=q>>1), byte
        //      (q&1)*512 + rl*16 + hi*8
        #pragma unroll
        for (int mt = 0; mt < 2; ++mt)
            #pragma unroll
            for (int nt = 0; nt < 4; ++nt)
                #pragma unroll
                for (int q = 0; q < 4; ++q) {
                    uint2 wvv; short* p = (short*)&wvv;
                    #pragma unroll
                    for (int r2 = 0; r2 < 4; ++r2)
                        p[r2] = bf16b(fmaxf(acc[nt][mt][q * 4 + r2], 0.f));
                    *(uint2*)(hb + (((mw * 2 + mt) * 8 + (nw * 4 + nt)) * 2
                                    + (q >> 1)) * 1024
                                 + (q & 1) * 512 + rl * 16 + hi * 8) = wvv;
                }
        __syncthreads();                   // h ready (acc dead here)

        if (e < NEXP) {
            // ---- layer 2 (single pass over full h) + layer 3 ----
            f32x16 acc2[2];
            #pragma unroll
            for (int q = 0; q < 16; ++q) { acc2[0][q] = 0.f; acc2[1][q] = 0.f; }
            #pragma unroll
            for (int jb = 0; jb < 2; ++jb)
                #pragma unroll
                for (int k2 = 0; k2 < 8; ++k2)
                    #pragma unroll
                    for (int kh = 0; kh < 2; ++kh) {
                        s16x8 hf = *(const s16x8*)(hb + ((wave * 8 + k2) * 2 + kh) * 1024
                                                   + lane * 16);
                        s16x8 wf = *(const s16x8*)(w2c
                            + ((((size_t)e * 2 + jb) * 8 + k2) * 2 + kh) * 1024
                            + lane * 16);
                        acc2[jb] = __builtin_amdgcn_mfma_f32_32x32x16_bf16(
                            wf, hf, acc2[jb], 0, 0, 0);
                    }
            // layer 3: lane m = wave*32+rl, j = jb*32 + r2+8q+4hi
            float part = 0.f;
            #pragma unroll
            for (int jb = 0; jb < 2; ++jb)
                #pragma unroll
                for (int q = 0; q < 4; ++q) {
                    f32x4 b2v = *(const f32x4*)(b2s + e * NH2 + jb * 32 + 8 * q + 4 * hi);
                    f32x4 w3v = *(const f32x4*)(w3s + e * NH2 + jb * 32 + 8 * q + 4 * hi);
                    #pragma unroll
                    for (int r2 = 0; r2 < 4; ++r2)
                        part += fmaxf(acc2[jb][q * 4 + r2] + b2v[r2], 0.f) * w3v[r2];
                }
            part += __shfl_xor(part, 32, 64);
            if (hi == 0)
                expl[(wave * 32 + rl) * NEXP + e] = part + b3s[e];
        } else {
            // ---- gate: logits -> softmax -> combine ----
            f32x16 acc3;
            #pragma unroll
            for (int q = 0; q < 16; ++q) acc3[q] = 0.f;
            #pragma unroll
            for (int k2 = 0; k2 < 8; ++k2)
                #pragma unroll
                for (int kh = 0; kh < 2; ++kh) {
                    s16x8 hf = *(const s16x8*)(hb + ((wave * 8 + k2) * 2 + kh) * 1024
                                               + lane * 16);
                    s16x8 gf = *(const s16x8*)(wgc + (k2 * 2 + kh) * 1024 + lane * 16);
                    acc3 = __builtin_amdgcn_mfma_f32_32x32x16_bf16(
                        gf, hf, acc3, 0, 0, 0);
                }
            const int m = wave * 32 + rl;
            float lv[16], mx = -1e30f;
            #pragma unroll
            for (int q = 0; q < 4; ++q)
                #pragma unroll
                for (int r2 = 0; r2 < 4; ++r2) {
                    int j = r2 + 8 * q + 4 * hi;
                    int rg = q * 4 + r2;
                    lv[rg] = (j < NEXP) ? (acc3[rg] + bg2s[j]) : -1e30f;
                    mx = fmaxf(mx, lv[rg]);
                }
            mx = fmaxf(mx, __shfl_xor(mx, 32, 64));
            float s = 0.f, pv[16];
            #pragma unroll
            for (int rg = 0; rg < 16; ++rg) {
                pv[rg] = (lv[rg] > -1e29f) ? __expf(lv[rg] - mx) : 0.f;
                s += pv[rg];
            }
            s += __shfl_xor(s, 32, 64);
            const float inv = 1.f / s;
            #pragma unroll
            for (int q = 0; q < 4; ++q)
                #pragma unroll
                for (int r2 = 0; r2 < 4; ++r2) {
                    int j = r2 + 8 * q + 4 * hi;
                    if (j < NEXP) {
                        float g  = pv[q * 4 + r2] * inv;
                        float eo = expl[m * NEXP + j];
                        size_t o = (size_t)(row0 + m) * NEXP + j;
                        out[o] = g * eo;                        // output
                        out[(size_t)BTOT * NEXP + o] = g;       // gate_scores
                        out[(size_t)2 * BTOT * NEXP + o] = eo;  // expert_outputs
                    }
                }
        }
        __syncthreads();                   // h reads done; next expert may stage
    }
}

extern "C" void kernel_launch(void* const* d_in, const int* in_sizes, int n_in,
                              void* d_out, int out_size, void* d_ws, size_t ws_size,
                              hipStream_t stream) {
    (void)in_sizes; (void)n_in; (void)out_size; (void)ws_size;
    const float* x   = (const float*)d_in[0];
    const float* W1  = (const float*)d_in[1];
    const float* b1  = (const float*)d_in[2];
    const float* W2  = (const float*)d_in[3];
    const float* b2  = (const float*)d_in[4];
    const float* W3  = (const float*)d_in[5];
    const float* b3  = (const float*)d_in[6];
    const float* Wg1 = (const float*)d_in[7];
    const float* bg1 = (const float*)d_in[8];
    const float* Wg2 = (const float*)d_in[9];
    const float* bg2 = (const float*)d_in[10];

    // ws layout (bf16): w1t 11*25*8192 | w2t 20480*8 | wg2t 1024*8 | xt [256][25][8192]
    __bf16* w1t  = (__bf16*)d_ws;
    __bf16* w2t  = w1t + (size_t)11 * 25 * 8192;
    __bf16* wg2t = w2t + (size_t)20480 * 8;
    __bf16* xt   = wg2t + (size_t)1024 * 8;

    hipFuncSetAttribute((const void*)moe_fused,
                        hipFuncAttributeMaxDynamicSharedMemorySize, LDS_TOTAL);

    prep_w1<<<1100, 256, 0, stream>>>(W1, b1, Wg1, bg1, w1t);
    prep_w2<<<80, 256, 0, stream>>>(W2, w2t);
    prep_wg2<<<4, 256, 0, stream>>>(Wg2, wg2t);
    prep_x<<<2048, 256, 0, stream>>>(x, xt);
    moe_fused<<<BTOT / BM, 512, LDS_TOTAL, stream>>>(
        xt, b2, W3, b3, bg2, w1t, w2t, wg2t, (float*)d_out);
}

// Round 17
// 329.060 us; speedup vs baseline: 1.2601x; 1.0574x over previous
//
#include <hip/hip_runtime.h>
#include <hip/hip_bf16.h>
#include <stdint.h>

// ---------------- problem dims ----------------
#define BTOT   65536
#define DIN    784
#define NH1    256
#define NH2    64
#define NEXP   10
#define BM     256
#define NKS1   25      // K1 = 800 (784 + bias row @784 + zeros), 25 steps of 32

// ---------------- LDS layout (bytes) ----------------
// 4-slot staging ring, 32 KB each (x 16K | w 16K). h (128 KB, FULL) overlays
// the whole ring — used only after the K-loop fully drains.
#define SLOT(s)   (lds + (s) * 32768)
#define EXPL_OFF  131072                   // [256 m][10 e] f32 = 10240
#define B2S_OFF   141312                   // [10][64] f32 = 2560
#define W3S_OFF   143872                   // [10][64] f32 = 2560
#define B3S_OFF   146432                   // 64
#define BG2S_OFF  146496                   // 64
#define LDS_TOTAL 146560

typedef short s16x8  __attribute__((ext_vector_type(8)));
typedef float f32x4  __attribute__((ext_vector_type(4)));
typedef float f32x16 __attribute__((ext_vector_type(16)));

__device__ __forceinline__ short bf16b(float v) {
    __bf16 b = (__bf16)v;
    return __builtin_bit_cast(short, b);
}

__device__ __forceinline__ void g2l16(const void* g, void* l) {
    __builtin_amdgcn_global_load_lds(
        (const __attribute__((address_space(1))) unsigned char*)g,
        (__attribute__((address_space(3))) unsigned char*)l, 16, 0, 0);
}

// ---------------- prep: fragment-order weights (bf16, b1 folded) ------------
// w1t [e11][ks25][nb8][kh2][lane64][8]: n=nb*32+(lane&31),
// k=ks*32+kh*16+(lane>>5)*8+j; k==784 -> bias; e==10 -> gate Wg1/bg1.
__global__ void prep_w1(const float* __restrict__ W1, const float* __restrict__ b1,
                        const float* __restrict__ Wg1, const float* __restrict__ bg1,
                        __bf16* __restrict__ dst) {
    int t = blockIdx.x * 256 + threadIdx.x;          // < 281600
    int lane = t & 63;
    int kh = (t >> 6) & 1;
    int nb = (t >> 7) & 7;
    int r  = t >> 10;
    int ks = r % 25, e = r / 25;
    int n  = nb * 32 + (lane & 31);
    int k0 = ks * 32 + kh * 16 + (lane >> 5) * 8;
    const float* src  = (e < NEXP) ? (W1 + (size_t)e * DIN * NH1) : Wg1;
    const float* bias = (e < NEXP) ? (b1 + e * NH1) : bg1;
    s16x8 o;
    #pragma unroll
    for (int j = 0; j < 8; ++j) {
        int k = k0 + j;
        float v = (k < DIN) ? src[(size_t)k * NH1 + n]
                            : ((k == DIN) ? bias[n] : 0.f);
        o[j] = bf16b(v);
    }
    *(s16x8*)((short*)dst + (size_t)t * 8) = o;
}

// w2t [e10][jb2][ks8][kh2][lane64][8]: n=jb*32+(lane&31), K2=256.
__global__ void prep_w2(const float* __restrict__ W2, __bf16* __restrict__ dst) {
    int t = blockIdx.x * 256 + threadIdx.x;          // < 20480
    int lane = t & 63;
    int kh = (t >> 6) & 1;
    int ks = (t >> 7) & 7;
    int jb = (t >> 10) & 1;
    int e  = t >> 11;
    int n  = jb * 32 + (lane & 31);
    int k0 = ks * 32 + kh * 16 + (lane >> 5) * 8;
    s16x8 o;
    #pragma unroll
    for (int j = 0; j < 8; ++j)
        o[j] = bf16b(W2[((size_t)e * NH1 + k0 + j) * NH2 + n]);
    *(s16x8*)((short*)dst + (size_t)t * 8) = o;
}

// wg2t [ks8][kh2][lane64][8]: col = lane&31 (valid <10), K2=256.
__global__ void prep_wg2(const float* __restrict__ Wg2, __bf16* __restrict__ dst) {
    int t = blockIdx.x * 256 + threadIdx.x;
    if (t >= 1024) return;
    int lane = t & 63;
    int kh = (t >> 6) & 1;
    int ks = t >> 7;
    int n  = lane & 31;
    int k0 = ks * 32 + kh * 16 + (lane >> 5) * 8;
    s16x8 o;
    #pragma unroll
    for (int j = 0; j < 8; ++j)
        o[j] = bf16b((n < NEXP) ? Wg2[(size_t)(k0 + j) * NEXP + n] : 0.f);
    *(s16x8*)((short*)dst + (size_t)t * 8) = o;
}

// ---- staging + body macros ----
#define STAGE(S, E, KS) {                                                     \
        const char* xs_ = xtc + ((size_t)(KS) << 14) + tid * 16;              \
        char* xd_ = SLOT(S) + tid * 16;                                       \
        g2l16(xs_, xd_); g2l16(xs_ + 8192, xd_ + 8192);                       \
        const char* ws_ = w1c + (((size_t)(E) * 25 + (KS)) << 14) + tid * 16; \
        char* wd_ = SLOT(S) + 16384 + tid * 16;                               \
        g2l16(ws_, wd_); g2l16(ws_ + 8192, wd_ + 8192); }

// w-only stage (e=0 path)
#define WSTAGE1(S, KS) {                                                      \
        const char* ws_ = w1c + ((size_t)(KS) << 14) + tid * 16;              \
        char* wd_ = SLOT(S) + 16384 + tid * 16;                               \
        g2l16(ws_, wd_); g2l16(ws_ + 8192, wd_ + 8192); }

// e=0: load 16 fp32 of x (row xrow, k-half xkh) into xf; ks=24 upper half is
// the bias-1 + zero pad (k=784..799).
#define XLOAD(KS) { if ((KS) < 24 || xkh == 0) {                              \
            _Pragma("unroll") for (int i4 = 0; i4 < 4; ++i4)                  \
                *(float4*)(xf + 4 * i4) =                                     \
                    *(const float4*)(xrp + (KS) * 32 + 4 * i4);               \
        } else { _Pragma("unroll") for (int i4 = 0; i4 < 16; ++i4)            \
                     xf[i4] = 0.f;                                            \
                 xf[0] = 1.f; } }

// e=0: convert + write to LDS slot x-region AND write-through fragment-order
// xt (global) for the e>=1 ring sweeps.
#define XWRITE(B, KS) { s16x8 l8, h8;                                         \
        _Pragma("unroll") for (int j = 0; j < 8; ++j) {                       \
            l8[j] = bf16b(xf[j]); h8[j] = bf16b(xf[8 + j]); }                 \
        *(s16x8*)(SLOT(B) + xoff)       = l8;                                 \
        *(s16x8*)(SLOT(B) + xoff + 512) = h8;                                 \
        char* xg_ = xtw + ((size_t)(KS) << 14) + xoff;                        \
        *(s16x8*)xg_ = l8; *(s16x8*)(xg_ + 512) = h8; }

#define COMPUTE(S) {                                                          \
        const char* ab = SLOT(S) + mw * 4096 + lane * 16;                     \
        const char* wb = SLOT(S) + 16384 + nw * 8192 + lane * 16;             \
        s16x8 xv[2][2], wv[4][2];                                             \
        _Pragma("unroll") for (int mt = 0; mt < 2; ++mt)                      \
            _Pragma("unroll") for (int kh = 0; kh < 2; ++kh)                  \
                xv[mt][kh] = *(const s16x8*)(ab + (mt * 2 + kh) * 1024);      \
        _Pragma("unroll") for (int nt = 0; nt < 4; ++nt)                      \
            _Pragma("unroll") for (int kh = 0; kh < 2; ++kh)                  \
                wv[nt][kh] = *(const s16x8*)(wb + (nt * 2 + kh) * 1024);      \
        _Pragma("unroll") for (int kh = 0; kh < 2; ++kh)                      \
            _Pragma("unroll") for (int nt = 0; nt < 4; ++nt)                  \
                _Pragma("unroll") for (int mt = 0; mt < 2; ++mt)              \
                    acc[nt][mt] = __builtin_amdgcn_mfma_f32_32x32x16_bf16(    \
                        wv[nt][kh], xv[mt][kh], acc[nt][mt], 0, 0, 0); }

// counted-vmcnt sync wall
#define RING_SYNC(VN) {                                                       \
        asm volatile("s_waitcnt vmcnt(" #VN ")" ::: "memory");                \
        __builtin_amdgcn_s_barrier();                                         \
        asm volatile("" ::: "memory"); }

// ring body (steady state): wait own stage (oldest 4 of 12 outstanding),
// barrier, compute, stage ks+3 into the slot read one body ago (WAR-safe).
#define BODY(S, KS) {                                                         \
        RING_SYNC(8)                                                          \
        COMPUTE(S)                                                            \
        STAGE(((S) + 3) & 3, e, (KS) + 3) }

// ---------------- fused MoE kernel ----------------
// 256 blocks x 512 thr (8 waves, 1 block/CU, 2 waves/SIMD). Per expert:
// 256x256 layer-1 GEMM, K-step 32. e=0: 2-phase dbuf that converts x fp32->
// bf16 (reg-staged) into the slot AND writes fragment-order xt to ws (fuses
// the former prep_x pass, saving ~55us of wall). e>=1 + gate: 4-slot LDS
// ring, depth-3 counted vmcnt (never 0 until the tail). h written FULL (ring
// overlay) so acc dies before acc2 is born -> no scratch spill.
// mfma(W, x): D[n][m], m = lane&31, n = (r&3)+8*(r>>2)+4*(lane>>5).
__global__ void __launch_bounds__(512)
__attribute__((amdgpu_waves_per_eu(2, 2)))
moe_fused(const float* __restrict__ x, __bf16* __restrict__ xt,
          const float* __restrict__ b2g, const float* __restrict__ W3,
          const float* __restrict__ b3, const float* __restrict__ bg2,
          const __bf16* __restrict__ w1t, const __bf16* __restrict__ w2t,
          const __bf16* __restrict__ wg2t, float* __restrict__ out)
{
    extern __shared__ char lds[];
    char*  hb   = lds;                     // FULL h: [mtile8][ks2_8][kh2][1024B]
    float* expl = (float*)(lds + EXPL_OFF);
    float* b2s  = (float*)(lds + B2S_OFF);
    float* w3s  = (float*)(lds + W3S_OFF);
    float* b3s  = (float*)(lds + B3S_OFF);
    float* bg2s = (float*)(lds + BG2S_OFF);

    const int tid  = threadIdx.x;
    const int lane = tid & 63;
    const int wave = tid >> 6;             // 0..7
    const int rl   = lane & 31;
    const int hi   = lane >> 5;
    const int mw   = wave >> 1;            // 0..3 (64-row slice)
    const int nw   = wave & 1;             // 0..1 (128-col half)
    const int row0 = blockIdx.x * BM;
    const char* w1c = (const char*)w1t;
    const char* w2c = (const char*)w2t;
    const char* wgc = (const char*)wg2t;
    const char* xtc = (const char*)xt + ((size_t)blockIdx.x * 25 << 14);
    char*       xtw = (char*)xt + ((size_t)blockIdx.x * 25 << 14);

    // e=0 x-staging coords: thread -> (row, k-half)
    const int xrow = tid >> 1, xkh = tid & 1;
    const float* xrp = x + (size_t)(row0 + xrow) * DIN + xkh * 16;
    const int xoff = ((xrow >> 5) * 2 + xkh) * 1024 + (xrow & 31) * 16;
    float xf[16];

    for (int i = tid; i < NEXP * NH2; i += 512) { b2s[i] = b2g[i]; w3s[i] = W3[i]; }
    if (tid < NEXP) { b3s[tid] = b3[tid]; bg2s[tid] = bg2[tid]; }
    __syncthreads();                       // drains vmcnt -> known 0

    f32x16 acc[4][2];                      // [nt][mt] (layer-1)

    #pragma unroll 1
    for (int e = 0; e <= NEXP; ++e) {
        #pragma unroll
        for (int nt = 0; nt < 4; ++nt)
            #pragma unroll
            for (int mt = 0; mt < 2; ++mt)
                #pragma unroll
                for (int q = 0; q < 16; ++q) acc[nt][mt][q] = 0.f;

        if (e == 0) {
            // ---- e=0: 2-phase dbuf (slots 0/1), x fp32->bf16 + xt write ----
            int cur = 0;
            XLOAD(0)
            WSTAGE1(0, 0)
            XWRITE(0, 0)
            __syncthreads();
            #pragma unroll 1
            for (int ks = 0; ks < NKS1; ++ks) {
                if (ks < 24) { XLOAD(ks + 1) WSTAGE1(cur ^ 1, ks + 1) }
                COMPUTE(cur)
                if (ks < 24) XWRITE(cur ^ 1, ks + 1)
                __syncthreads();
                cur ^= 1;
            }
        } else {
            // ---- e>=1 / gate: 4-slot depth-3 counted ring ----
            STAGE(0, e, 0)
            STAGE(1, e, 1)
            STAGE(2, e, 2)
            #pragma unroll 1
            for (int T = 0; T < 5; ++T) {
                const int k4 = 4 * T;
                BODY(0, k4)
                BODY(1, k4 + 1)
                BODY(2, k4 + 2)
                BODY(3, k4 + 3)
            }
            BODY(0, 20)                    // stages ks=23 -> slot 3
            BODY(1, 21)                    // stages ks=24 -> slot 0
            RING_SYNC(8)  COMPUTE(2)       // ks=22 (no stage)
            RING_SYNC(4)  COMPUTE(3)       // ks=23
            RING_SYNC(0)  COMPUTE(0)       // ks=24
            __syncthreads();               // all ring reads done; h may overlay
        }

        // ---- h-write (FULL): value (nt,mt,q,r2) ->
        //      h[m=(mw*2+mt)*32+rl][n=nw*128+nt*32+(r2+8q+4hi)]
        #pragma unroll
        for (int mt = 0; mt < 2; ++mt)
            #pragma unroll
            for (int nt = 0; nt < 4; ++nt)
                #pragma unroll
                for (int q = 0; q < 4; ++q) {
                    uint2 wvv; short* p = (short*)&wvv;
                    #pragma unroll
                    for (int r2 = 0; r2 < 4; ++r2)
                        p[r2] = bf16b(fmaxf(acc[nt][mt][q * 4 + r2], 0.f));
                    *(uint2*)(hb + (((mw * 2 + mt) * 8 + (nw * 4 + nt)) * 2
                                    + (q >> 1)) * 1024
                                 + (q & 1) * 512 + rl * 16 + hi * 8) = wvv;
                }
        __syncthreads();                   // h ready (acc dead here)

        if (e < NEXP) {
            // ---- layer 2 (single pass over full h) + layer 3 ----
            f32x16 acc2[2];
            #pragma unroll
            for (int q = 0; q < 16; ++q) { acc2[0][q] = 0.f; acc2[1][q] = 0.f; }
            #pragma unroll
            for (int jb = 0; jb < 2; ++jb)
                #pragma unroll
                for (int k2 = 0; k2 < 8; ++k2)
                    #pragma unroll
                    for (int kh = 0; kh < 2; ++kh) {
                        s16x8 hf = *(const s16x8*)(hb + ((wave * 8 + k2) * 2 + kh) * 1024
                                                   + lane * 16);
                        s16x8 wf = *(const s16x8*)(w2c
                            + ((((size_t)e * 2 + jb) * 8 + k2) * 2 + kh) * 1024
                            + lane * 16);
                        acc2[jb] = __builtin_amdgcn_mfma_f32_32x32x16_bf16(
                            wf, hf, acc2[jb], 0, 0, 0);
                    }
            // layer 3: lane m = wave*32+rl, j = jb*32 + r2+8q+4hi
            float part = 0.f;
            #pragma unroll
            for (int jb = 0; jb < 2; ++jb)
                #pragma unroll
                for (int q = 0; q < 4; ++q) {
                    f32x4 b2v = *(const f32x4*)(b2s + e * NH2 + jb * 32 + 8 * q + 4 * hi);
                    f32x4 w3v = *(const f32x4*)(w3s + e * NH2 + jb * 32 + 8 * q + 4 * hi);
                    #pragma unroll
                    for (int r2 = 0; r2 < 4; ++r2)
                        part += fmaxf(acc2[jb][q * 4 + r2] + b2v[r2], 0.f) * w3v[r2];
                }
            part += __shfl_xor(part, 32, 64);
            if (hi == 0)
                expl[(wave * 32 + rl) * NEXP + e] = part + b3s[e];
        } else {
            // ---- gate: logits -> softmax -> combine ----
            f32x16 acc3;
            #pragma unroll
            for (int q = 0; q < 16; ++q) acc3[q] = 0.f;
            #pragma unroll
            for (int k2 = 0; k2 < 8; ++k2)
                #pragma unroll
                for (int kh = 0; kh < 2; ++kh) {
                    s16x8 hf = *(const s16x8*)(hb + ((wave * 8 + k2) * 2 + kh) * 1024
                                               + lane * 16);
                    s16x8 gf = *(const s16x8*)(wgc + (k2 * 2 + kh) * 1024 + lane * 16);
                    acc3 = __builtin_amdgcn_mfma_f32_32x32x16_bf16(
                        gf, hf, acc3, 0, 0, 0);
                }
            const int m = wave * 32 + rl;
            float lv[16], mx = -1e30f;
            #pragma unroll
            for (int q = 0; q < 4; ++q)
                #pragma unroll
                for (int r2 = 0; r2 < 4; ++r2) {
                    int j = r2 + 8 * q + 4 * hi;
                    int rg = q * 4 + r2;
                    lv[rg] = (j < NEXP) ? (acc3[rg] + bg2s[j]) : -1e30f;
                    mx = fmaxf(mx, lv[rg]);
                }
            mx = fmaxf(mx, __shfl_xor(mx, 32, 64));
            float s = 0.f, pv[16];
            #pragma unroll
            for (int rg = 0; rg < 16; ++rg) {
                pv[rg] = (lv[rg] > -1e29f) ? __expf(lv[rg] - mx) : 0.f;
                s += pv[rg];
            }
            s += __shfl_xor(s, 32, 64);
            const float inv = 1.f / s;
            #pragma unroll
            for (int q = 0; q < 4; ++q)
                #pragma unroll
                for (int r2 = 0; r2 < 4; ++r2) {
                    int j = r2 + 8 * q + 4 * hi;
                    if (j < NEXP) {
                        float g  = pv[q * 4 + r2] * inv;
                        float eo = expl[m * NEXP + j];
                        size_t o = (size_t)(row0 + m) * NEXP + j;
                        out[o] = g * eo;                        // output
                        out[(size_t)BTOT * NEXP + o] = g;       // gate_scores
                        out[(size_t)2 * BTOT * NEXP + o] = eo;  // expert_outputs
                    }
                }
        }
        __syncthreads();                   // h reads done; next expert may stage
    }
}

extern "C" void kernel_launch(void* const* d_in, const int* in_sizes, int n_in,
                              void* d_out, int out_size, void* d_ws, size_t ws_size,
                              hipStream_t stream) {
    (void)in_sizes; (void)n_in; (void)out_size; (void)ws_size;
    const float* x   = (const float*)d_in[0];
    const float* W1  = (const float*)d_in[1];
    const float* b1  = (const float*)d_in[2];
    const float* W2  = (const float*)d_in[3];
    const float* b2  = (const float*)d_in[4];
    const float* W3  = (const float*)d_in[5];
    const float* b3  = (const float*)d_in[6];
    const float* Wg1 = (const float*)d_in[7];
    const float* bg1 = (const float*)d_in[8];
    const float* Wg2 = (const float*)d_in[9];
    const float* bg2 = (const float*)d_in[10];

    // ws layout (bf16): w1t 11*25*8192 | w2t 20480*8 | wg2t 1024*8 | xt [256][25][8192]
    __bf16* w1t  = (__bf16*)d_ws;
    __bf16* w2t  = w1t + (size_t)11 * 25 * 8192;
    __bf16* wg2t = w2t + (size_t)20480 * 8;
    __bf16* xt   = wg2t + (size_t)1024 * 8;

    hipFuncSetAttribute((const void*)moe_fused,
                        hipFuncAttributeMaxDynamicSharedMemorySize, LDS_TOTAL);

    prep_w1<<<1100, 256, 0, stream>>>(W1, b1, Wg1, bg1, w1t);
    prep_w2<<<80, 256, 0, stream>>>(W2, w2t);
    prep_wg2<<<4, 256, 0, stream>>>(Wg2, wg2t);
    moe_fused<<<BTOT / BM, 512, LDS_TOTAL, stream>>>(
        x, xt, b2, W3, b3, bg2, w1t, w2t, wg2t, (float*)d_out);
}